// Round 7
// baseline (316.173 us; speedup 1.0000x reference)
//
#include <hip/hip_runtime.h>

// Problem constants (fixed by the reference)
#define C_ROW 128            // lv row space actually consumable (wids in [0,128))
#define C_TOT 160            // combined rows feeding the scatter
#define R_    64
#define D_    4096
#define B_TOK 256
#define NENT  (C_TOT * R_)   // 10240 scatter entries
#define KS    8              // k-split for stage 1
#define KSPAN (D_ / KS)      // 512 floats per slice
#define LVN   (C_ROW * R_)   // 8192 lv entries
#define NCAP  256            // per-token entry capacity (mean 40, max ~62)
#define CH    4              // D-chunks per token in stage 2
#define NBLK  (C_ROW * KS)   // 1024 blocks: S1 units == S2 units (256 tok x 4 ch)

typedef float float4v __attribute__((ext_vector_type(4)));

// Device-global scratch (capture-safe; g_lvp fully rewritten every call).
__device__ float    g_lvp[KS][LVN];   // stage-1 partials, 256 KB
__device__ unsigned g_bar;            // monotonic barrier counter (grows forever;
                                      // target arithmetic makes it replay-safe)

// ---------------------------------------------------------------------------
// Fused kernel: phase A = lv partials (R4's verified s1 body),
// grid barrier, phase B = per-token gather (R6's verified s2 body).
// grid = 1024 blocks x 256 threads = 4 blocks/CU -> all co-resident
// (16 waves/CU of 32, ~4 KB LDS, low VGPR), so the spin barrier is safe.
// ---------------------------------------------------------------------------
__global__ __launch_bounds__(256) void fused(const float* __restrict__ A,
                                             const float* __restrict__ Bm,
                                             const float* __restrict__ x,
                                             const int* __restrict__ xids,
                                             const int* __restrict__ wids,
                                             float* __restrict__ out) {
  const int b   = blockIdx.x;
  const int tid = threadIdx.x;

  // ---------------- Phase A: S1 (lv partials) ----------------
  {
    const int c   = b >> 3;            // lv row, c < 128
    const int ks  = b & (KS - 1);      // k-slice
    const int r   = tid & 63;
    const int wv  = tid >> 6;          // wave: quarter of this k-slice
    const int w   = wids[c];           // adapter
    const int tok = xids[c * R_ + r];

    const float* __restrict__ xrow = x + (size_t)tok * D_;
    const float* __restrict__ acol = A + (size_t)w * (D_ * R_) + r;

    const int k0 = ks * KSPAN + wv * (KSPAN / 4);   // 128 k's per wave
    float acc = 0.f;
    #pragma unroll 4
    for (int k = k0; k < k0 + (KSPAN / 4); k += 4) {
      const float4v xv = *reinterpret_cast<const float4v*>(xrow + k);
      acc = fmaf(xv[0], acol[(size_t)(k + 0) * R_], acc);
      acc = fmaf(xv[1], acol[(size_t)(k + 1) * R_], acc);
      acc = fmaf(xv[2], acol[(size_t)(k + 2) * R_], acc);
      acc = fmaf(xv[3], acol[(size_t)(k + 3) * R_], acc);
    }

    __shared__ float part[4][64];
    part[wv][r] = acc;
    __syncthreads();
    if (tid < 64)
      g_lvp[ks][c * R_ + tid] =
          part[0][tid] + part[1][tid] + part[2][tid] + part[3][tid];
  }

  // ---------------- Grid barrier (monotonic counter, replay-safe) ----------
  __threadfence();                      // flush g_lvp writes device-wide
  __syncthreads();
  if (tid == 0) {
    const unsigned my =
        __hip_atomic_fetch_add(&g_bar, 1u, __ATOMIC_ACQ_REL,
                               __HIP_MEMORY_SCOPE_AGENT) + 1u;
    const unsigned target = ((my + NBLK - 1u) / NBLK) * NBLK;
    while (__hip_atomic_load(&g_bar, __ATOMIC_ACQUIRE,
                             __HIP_MEMORY_SCOPE_AGENT) < target)
      __builtin_amdgcn_s_sleep(2);
  }
  __syncthreads();

  // ---------------- Phase B: S2 (per-token gather) ----------------
  const int t   = b >> 2;              // token
  const int ch  = b & (CH - 1);        // D-chunk
  const int d0  = ch * (D_ / CH) + tid * 4;

  __shared__ int   s_n;
  __shared__ int   s_idx[NCAP];
  __shared__ float s_cf[NCAP];
  if (tid == 0) s_n = 0;
  __syncthreads();
  for (int i = tid; i < NENT; i += 256) {
    if (xids[i] == t) {
      const int p = atomicAdd(&s_n, 1);
      if (p < NCAP) s_idx[p] = wids[i >> 6] * R_ + (i & 63);  // lv/B row index
    }
  }
  __syncthreads();
  const int n = (s_n < NCAP) ? s_n : NCAP;
  if (tid < n) {
    const int idx = s_idx[tid];
    float cf = 0.f;
    #pragma unroll
    for (int p = 0; p < KS; ++p) cf += g_lvp[p][idx];
    s_cf[tid] = cf;
  }
  __syncthreads();

  float4v acc;
  acc[0] = acc[1] = acc[2] = acc[3] = 0.f;

  #pragma unroll 2
  for (int j = 0; j < n; ++j) {
    const int   idx = s_idx[j];
    const float cf  = s_cf[j];
    const float4v bv =
        *reinterpret_cast<const float4v*>(Bm + (size_t)idx * D_ + d0);
    acc[0] = fmaf(cf, bv[0], acc[0]);
    acc[1] = fmaf(cf, bv[1], acc[1]);
    acc[2] = fmaf(cf, bv[2], acc[2]);
    acc[3] = fmaf(cf, bv[3], acc[3]);
  }

  float4v o;
  o[0] = 2.0f * acc[0]; o[1] = 2.0f * acc[1];
  o[2] = 2.0f * acc[2]; o[3] = 2.0f * acc[3];
  *reinterpret_cast<float4v*>(out + (size_t)t * D_ + d0) = o;
}

// ---------------------------------------------------------------------------
extern "C" void kernel_launch(void* const* d_in, const int* in_sizes, int n_in,
                              void* d_out, int out_size, void* d_ws, size_t ws_size,
                              hipStream_t stream) {
  const float* lora_A = (const float*)d_in[0];
  const float* lora_B = (const float*)d_in[1];
  const float* x      = (const float*)d_in[2];
  const int* xids = (const int*)d_in[3];
  const int* wids = (const int*)d_in[4];
  float* out = (float*)d_out;

  hipLaunchKernelGGL(fused, dim3(NBLK), dim3(256), 0, stream,
                     lora_A, lora_B, x, xids, wids, out);
}

// Round 8
// 64.179 us; speedup vs baseline: 4.9264x; 4.9264x over previous
//
#include <hip/hip_runtime.h>

// Problem constants (fixed by the reference)
#define C_ROW 128            // lv rows: wids values lie in [0,128)
#define C_TOT 160            // combined rows feeding the scatter
#define R_    64
#define D_    4096
#define B_TOK 256
#define NENT  (C_TOT * R_)   // 10240 scatter entries
#define KS    32             // k-split for stage 1
#define KSPAN (D_ / KS)      // 128 floats per slice
#define LVN   (C_ROW * R_)   // 8192 lv entries
#define NCAP  256            // per-token entry capacity (mean 40, max ~62)
#define CH    4              // D-chunks per token in stage 2

typedef float float4v __attribute__((ext_vector_type(4)));

// Device-global scratch (capture-safe; fully rewritten every call).
__device__ float g_lvp[KS][LVN];   // stage-1 partials, 1 MB
__device__ float g_lv[LVN];        // reduced lv table, 32 KB

// ---------------------------------------------------------------------------
// S1: lv partials. grid = C_ROW*KS = 4096 blocks, 256 thr, 32 KB LDS tile
// -> 4 blocks/CU. x token rows staged coalesced into LDS (XOR-swizzled
// float4 cols); A reads lane-over-r 256B-coalesced, 32-deep per thread.
// ---------------------------------------------------------------------------
__global__ __launch_bounds__(256) void s1(const float* __restrict__ A,
                                          const float* __restrict__ x,
                                          const int* __restrict__ xids,
                                          const int* __restrict__ wids) {
  const int b   = blockIdx.x;
  const int c   = b >> 5;            // lv row, c < 128
  const int ks  = b & (KS - 1);      // k-slice
  const int tid = threadIdx.x;
  const int r   = tid & 63;
  const int wv  = tid >> 6;

  __shared__ int     s_tok[64];
  __shared__ float4v xs[64][KSPAN / 4];   // [row][swizzled float4 col] 32 KB
  __shared__ float   part[4][64];

  if (tid < 64) s_tok[tid] = xids[c * R_ + tid];
  __syncthreads();

  const int k0 = ks * KSPAN;                // float offset within a row
  // Stage: each wave-instr covers 2 rows x 512B contiguous.
  #pragma unroll
  for (int i = 0; i < 8; ++i) {
    const int flat = i * 256 + tid;
    const int row  = flat >> 5;             // 0..63
    const int c4   = flat & 31;             // float4 col 0..31
    xs[row][c4 ^ (row & 7)] = *reinterpret_cast<const float4v*>(
        x + (size_t)s_tok[row] * D_ + k0 + c4 * 4);
  }
  __syncthreads();

  // Compute: lane = r reads its own LDS row; wave wv covers 32 k's.
  const int a = wids[c];
  const float* __restrict__ acol =
      A + (size_t)a * (D_ * R_) + (size_t)k0 * R_ + r;

  float acc = 0.f;
  #pragma unroll
  for (int j8 = 0; j8 < 8; ++j8) {
    const int j = wv * 8 + j8;              // logical float4 col
    const float4v xv = xs[r][j ^ (r & 7)];
    const int kk = j * 4;
    acc = fmaf(xv[0], acol[(size_t)(kk + 0) * R_], acc);
    acc = fmaf(xv[1], acol[(size_t)(kk + 1) * R_], acc);
    acc = fmaf(xv[2], acol[(size_t)(kk + 2) * R_], acc);
    acc = fmaf(xv[3], acol[(size_t)(kk + 3) * R_], acc);
  }

  part[wv][r] = acc;
  __syncthreads();
  if (tid < 64)
    g_lvp[ks][c * R_ + tid] =
        part[0][tid] + part[1][tid] + part[2][tid] + part[3][tid];
}

// ---------------------------------------------------------------------------
// S1R: collapse the KS partials -> g_lv. grid = LVN/256 = 32 blocks.
// Coalesced: thread i sums column i across the 32 partial tables.
// ---------------------------------------------------------------------------
__global__ __launch_bounds__(256) void s1r() {
  const int i = blockIdx.x * 256 + threadIdx.x;
  float s = 0.f;
  #pragma unroll
  for (int p = 0; p < KS; ++p) s += g_lvp[p][i];
  g_lv[i] = s;
}

// ---------------------------------------------------------------------------
// S2: per-token gather. grid = B_TOK*CH = 1024 blocks, 256 threads.
// Each block: one token, D/CH = 1024 floats (float4 per thread).
// Entry list via parallel filter over xids (L2-resident, 40 KB).
// ---------------------------------------------------------------------------
__global__ __launch_bounds__(256) void s2(const float* __restrict__ Bm,
                                          const int* __restrict__ xids,
                                          const int* __restrict__ wids,
                                          float* __restrict__ out) {
  const int t   = blockIdx.x >> 2;
  const int ch  = blockIdx.x & (CH - 1);
  const int tid = threadIdx.x;
  const int d0  = ch * (D_ / CH) + tid * 4;

  __shared__ int   s_n;
  __shared__ int   s_idx[NCAP];
  __shared__ float s_cf[NCAP];
  if (tid == 0) s_n = 0;
  __syncthreads();
  for (int i = tid; i < NENT; i += 256) {
    if (xids[i] == t) {
      const int p = atomicAdd(&s_n, 1);
      if (p < NCAP) s_idx[p] = wids[i >> 6] * R_ + (i & 63);  // lv/B row index
    }
  }
  __syncthreads();
  const int n = (s_n < NCAP) ? s_n : NCAP;
  if (tid < n) s_cf[tid] = g_lv[s_idx[tid]];
  __syncthreads();

  float4v acc;
  acc[0] = acc[1] = acc[2] = acc[3] = 0.f;

  #pragma unroll 4
  for (int j = 0; j < n; ++j) {
    const int   idx = s_idx[j];
    const float cf  = s_cf[j];
    const float4v bv =
        *reinterpret_cast<const float4v*>(Bm + (size_t)idx * D_ + d0);
    acc[0] = fmaf(cf, bv[0], acc[0]);
    acc[1] = fmaf(cf, bv[1], acc[1]);
    acc[2] = fmaf(cf, bv[2], acc[2]);
    acc[3] = fmaf(cf, bv[3], acc[3]);
  }

  float4v o;
  o[0] = 2.0f * acc[0]; o[1] = 2.0f * acc[1];
  o[2] = 2.0f * acc[2]; o[3] = 2.0f * acc[3];
  *reinterpret_cast<float4v*>(out + (size_t)t * D_ + d0) = o;
}

// ---------------------------------------------------------------------------
extern "C" void kernel_launch(void* const* d_in, const int* in_sizes, int n_in,
                              void* d_out, int out_size, void* d_ws, size_t ws_size,
                              hipStream_t stream) {
  const float* lora_A = (const float*)d_in[0];
  const float* lora_B = (const float*)d_in[1];
  const float* x      = (const float*)d_in[2];
  const int* xids = (const int*)d_in[3];
  const int* wids = (const int*)d_in[4];
  float* out = (float*)d_out;

  hipLaunchKernelGGL(s1, dim3(C_ROW * KS), dim3(256), 0, stream,
                     lora_A, x, xids, wids);
  hipLaunchKernelGGL(s1r, dim3(LVN / 256), dim3(256), 0, stream);
  hipLaunchKernelGGL(s2, dim3(B_TOK * CH), dim3(256), 0, stream,
                     lora_B, xids, wids, out);
}